// Round 2
// baseline (286.523 us; speedup 1.0000x reference)
//
#include <hip/hip_runtime.h>
#include <math.h>

typedef short bf16x8 __attribute__((ext_vector_type(8)));
typedef float f32x4 __attribute__((ext_vector_type(4)));

#define N0v 120000
#define N1v 12000
#define N2v 1024
#define F_INv 602
#define KPADv 608
#define HCv 64
#define NCLSv 41
#define NEGv 0.2f

__device__ __forceinline__ float b2f(unsigned short u) {
  return __uint_as_float(((unsigned int)u) << 16);
}
__device__ __forceinline__ unsigned short f2b(float f) {
  unsigned int u = __float_as_uint(f);
  u += 0x7fffu + ((u >> 16) & 1u);
  return (unsigned short)(u >> 16);
}
__device__ __forceinline__ float leaky(float v) {
  return v > 0.f ? v : NEGv * v;
}

// ---------------- W1 transpose+convert: Wt[n][kpad] = bf16(W1[k][n]) ----------------
__global__ void k_transposeW1(const float* __restrict__ W1,
                              unsigned short* __restrict__ Wt) {
  int idx = blockIdx.x * 256 + threadIdx.x;
  if (idx >= HCv * KPADv) return;
  int n = idx / KPADv, k = idx % KPADv;
  Wt[idx] = (k < F_INv) ? f2b(W1[k * HCv + n]) : (unsigned short)0;
}

// ---------------- GEMM: H = x[120000x602] @ W1[602x64] (f32 in, bf16 MFMA, bf16 out) ----------------
__global__ __launch_bounds__(256) void k_gemm1(const float* __restrict__ x,
                                               const unsigned short* __restrict__ Wt,
                                               unsigned short* __restrict__ H) {
  __shared__ unsigned short As[64][40];  // 80B row stride (16B aligned)
  __shared__ unsigned short Bs[64][40];  // Bs[n][k] = W1[k][n]
  const int tid = threadIdx.x;
  const int wave = tid >> 6, lane = tid & 63;
  const int block_row = blockIdx.x * 64;
  const int r = tid >> 2, seg = tid & 3;

  f32x4 acc[4];
#pragma unroll
  for (int n = 0; n < 4; ++n) acc[n] = (f32x4){0.f, 0.f, 0.f, 0.f};

  for (int kt = 0; kt < 19; ++kt) {
    const int k = kt * 32 + seg * 8;
    // B: bf16 rows of Wt, padded to 608 -> always aligned 16B, pad reads are zeros
    uint4 bv = *reinterpret_cast<const uint4*>(Wt + (size_t)r * KPADv + k);
    // A: f32 -> bf16 convert
    float fa[8];
    {
      const float* sa = x + (size_t)(block_row + r) * F_INv + k;
      if (k + 8 <= F_INv) {
#pragma unroll
        for (int q = 0; q < 4; ++q) {
          float2 t = *reinterpret_cast<const float2*>(sa + q * 2);
          fa[2 * q] = t.x;
          fa[2 * q + 1] = t.y;
        }
      } else {
#pragma unroll
        for (int q = 0; q < 8; ++q) fa[q] = (k + q < F_INv) ? sa[q] : 0.f;
      }
    }
    unsigned int av[4];
#pragma unroll
    for (int q = 0; q < 4; ++q)
      av[q] = (unsigned int)f2b(fa[2 * q]) | ((unsigned int)f2b(fa[2 * q + 1]) << 16);

    __syncthreads();  // previous iter's frag reads done
    *reinterpret_cast<uint4*>(&As[r][seg * 8]) = make_uint4(av[0], av[1], av[2], av[3]);
    *reinterpret_cast<uint4*>(&Bs[r][seg * 8]) = make_uint4(bv.x, bv.y, bv.z, bv.w);
    __syncthreads();

    const int arow = wave * 16 + (lane & 15);
    const int kb = (lane >> 4) * 8;
    bf16x8 a = *reinterpret_cast<const bf16x8*>(&As[arow][kb]);
#pragma unroll
    for (int n = 0; n < 4; ++n) {
      bf16x8 b = *reinterpret_cast<const bf16x8*>(&Bs[n * 16 + (lane & 15)][kb]);
      acc[n] = __builtin_amdgcn_mfma_f32_16x16x32_bf16(a, b, acc[n], 0, 0, 0);
    }
  }
  // epilogue: col = n*16 + (lane&15), row = wave*16 + (lane>>4)*4 + j  [m89 mapping]
#pragma unroll
  for (int n = 0; n < 4; ++n) {
#pragma unroll
    for (int j = 0; j < 4; ++j) {
      int row = block_row + wave * 16 + (lane >> 4) * 4 + j;
      int col = n * 16 + (lane & 15);
      H[(size_t)row * HCv + col] = f2b(acc[n][j]);
    }
  }
}

// ---------------- per-row attention dots: a_s1[i,h], a_d1[i,h] ----------------
__global__ __launch_bounds__(256) void k_dots1(const unsigned short* __restrict__ H,
                                               const float* __restrict__ att_s,
                                               const float* __restrict__ att_d,
                                               float* __restrict__ as1,
                                               float* __restrict__ ad1) {
  __shared__ float ss[64], sdd[64];
  int tid = threadIdx.x;
  if (tid < 64) {
    ss[tid] = att_s[tid];
    sdd[tid] = att_d[tid];
  }
  __syncthreads();
  int i = blockIdx.x * 256 + tid;
  if (i >= N0v) return;
  float f[64];
  const unsigned short* hp = H + (size_t)i * HCv;
#pragma unroll
  for (int q = 0; q < 8; ++q) {
    uint4 u = *reinterpret_cast<const uint4*>(hp + q * 8);
    f[q * 8 + 0] = b2f((unsigned short)(u.x & 0xffff));
    f[q * 8 + 1] = b2f((unsigned short)(u.x >> 16));
    f[q * 8 + 2] = b2f((unsigned short)(u.y & 0xffff));
    f[q * 8 + 3] = b2f((unsigned short)(u.y >> 16));
    f[q * 8 + 4] = b2f((unsigned short)(u.z & 0xffff));
    f[q * 8 + 5] = b2f((unsigned short)(u.z >> 16));
    f[q * 8 + 6] = b2f((unsigned short)(u.w & 0xffff));
    f[q * 8 + 7] = b2f((unsigned short)(u.w >> 16));
  }
#pragma unroll
  for (int h = 0; h < 8; ++h) {
    float s = 0.f, d = 0.f;
#pragma unroll
    for (int c = 0; c < 8; ++c) {
      s += f[h * 8 + c] * ss[h * 8 + c];
      d += f[h * 8 + c] * sdd[h * 8 + c];
    }
    as1[(size_t)i * 8 + h] = s;
    if (i < N1v) ad1[(size_t)i * 8 + h] = d;
  }
}

// ---------------- CSR build ----------------
__global__ void k_count(const int* __restrict__ dst, int E, int* __restrict__ deg) {
  int e = blockIdx.x * 256 + threadIdx.x;
  if (e < E) atomicAdd(&deg[dst[e]], 1);
}

__global__ __launch_bounds__(1024) void k_scan(const int* __restrict__ deg,
                                               int* __restrict__ rs,
                                               int* __restrict__ cur, int n) {
  __shared__ int sd[1024];
  __shared__ int carry_s;
  int tid = threadIdx.x;
  if (tid == 0) carry_s = 0;
  __syncthreads();
  for (int base = 0; base < n; base += 1024) {
    int i = base + tid;
    int v = (i < n) ? deg[i] : 0;
    sd[tid] = v;
    __syncthreads();
    for (int off = 1; off < 1024; off <<= 1) {
      int t = (tid >= off) ? sd[tid - off] : 0;
      __syncthreads();
      sd[tid] += t;
      __syncthreads();
    }
    int incl = sd[tid];
    int carry = carry_s;
    if (i < n) {
      int ex = carry + incl - v;
      rs[i] = ex;
      cur[i] = ex;
    }
    __syncthreads();
    if (tid == 1023) carry_s = carry + incl;
    __syncthreads();
  }
  if (tid == 0) rs[n] = carry_s;
}

__global__ void k_scatter(const int* __restrict__ src, const int* __restrict__ dst, int E,
                          int* __restrict__ cur, int* __restrict__ esrc) {
  int e = blockIdx.x * 256 + threadIdx.x;
  if (e < E) {
    int p = atomicAdd(&cur[dst[e]], 1);
    esrc[p] = src[e];
  }
}

// ---------------- layer-1 attention: one wave per dst node ----------------
__global__ __launch_bounds__(256) void k_attn1(const float* __restrict__ as1,
                                               const float* __restrict__ ad1,
                                               const int* __restrict__ rs,
                                               const int* __restrict__ esrc,
                                               const unsigned short* __restrict__ H,
                                               const float* __restrict__ b1,
                                               float* __restrict__ h1) {
  int wave = threadIdx.x >> 6, lane = threadIdx.x & 63;
  int d = blockIdx.x * 4 + wave;
  if (d >= N1v) return;
  int h = lane >> 3;
  int beg = rs[d], end = rs[d + 1];
  float adh = ad1[(size_t)d * 8 + h];
  float a_self = leaky(as1[(size_t)d * 8 + h] + adh);
  float m = a_self;
  for (int p = beg; p < end; ++p) {
    int s = esrc[p];
    m = fmaxf(m, leaky(as1[(size_t)s * 8 + h] + adh));
  }
  float ssum, acc;
  {
    float e = __expf(a_self - m);
    ssum = e;
    acc = e * b2f(H[(size_t)d * HCv + lane]);
  }
  for (int p = beg; p < end; ++p) {
    int s = esrc[p];
    float e = __expf(leaky(as1[(size_t)s * 8 + h] + adh) - m);
    ssum += e;
    acc += e * b2f(H[(size_t)s * HCv + lane]);
  }
  float o = acc / ssum + b1[lane];
  o = o > 0.f ? o : expm1f(o);  // ELU
  h1[(size_t)d * HCv + lane] = o;
}

// ---------------- layer-2 features: g = h1 @ W2, + attention dots ----------------
__global__ __launch_bounds__(256) void k_l2feat(const float* __restrict__ h1,
                                                const float* __restrict__ W2,
                                                const float* __restrict__ a_s,
                                                const float* __restrict__ a_d,
                                                float* __restrict__ g,
                                                float* __restrict__ as2,
                                                float* __restrict__ ad2) {
  __shared__ float w[64 * 41];
  __shared__ float vs[41], vd[41];
  int tid = threadIdx.x;
  for (int idx = tid; idx < 64 * 41; idx += 256) w[idx] = W2[idx];
  if (tid < 41) {
    vs[tid] = a_s[tid];
    vd[tid] = a_d[tid];
  }
  __syncthreads();
  int i = blockIdx.x * 256 + tid;
  if (i >= N1v) return;
  float r[64];
  const float4* hp = reinterpret_cast<const float4*>(h1 + (size_t)i * HCv);
#pragma unroll
  for (int q = 0; q < 16; ++q) {
    float4 t = hp[q];
    r[q * 4 + 0] = t.x; r[q * 4 + 1] = t.y; r[q * 4 + 2] = t.z; r[q * 4 + 3] = t.w;
  }
  float sa = 0.f, da = 0.f;
  for (int c = 0; c < 41; ++c) {
    float a = 0.f;
#pragma unroll
    for (int k = 0; k < 64; ++k) a += r[k] * w[k * 41 + c];
    g[(size_t)i * 41 + c] = a;
    sa += a * vs[c];
    da += a * vd[c];
  }
  as2[i] = sa;
  ad2[i] = da;
}

// ---------------- layer-2 attention + log_softmax: one wave per dst ----------------
__global__ __launch_bounds__(256) void k_attn2(const float* __restrict__ as2,
                                               const float* __restrict__ ad2,
                                               const int* __restrict__ rs,
                                               const int* __restrict__ esrc,
                                               const float* __restrict__ g,
                                               const float* __restrict__ b2,
                                               float* __restrict__ out) {
  int wave = threadIdx.x >> 6, lane = threadIdx.x & 63;
  int d = blockIdx.x * 4 + wave;
  if (d >= N2v) return;
  int beg = rs[d], end = rs[d + 1];
  float ad = ad2[d];
  float a_self = leaky(as2[d] + ad);
  float m = a_self;
  for (int p = beg; p < end; ++p) m = fmaxf(m, leaky(as2[esrc[p]] + ad));
  float ssum, acc;
  {
    float e = __expf(a_self - m);
    ssum = e;
    acc = (lane < 41) ? e * g[(size_t)d * 41 + lane] : 0.f;
  }
  for (int p = beg; p < end; ++p) {
    int s = esrc[p];
    float e = __expf(leaky(as2[s] + ad) - m);
    ssum += e;
    if (lane < 41) acc += e * g[(size_t)s * 41 + lane];
  }
  float logit = acc / ssum + ((lane < 41) ? b2[lane] : 0.f);
  float v = (lane < 41) ? logit : -INFINITY;
  float mx = v;
#pragma unroll
  for (int o = 32; o >= 1; o >>= 1) mx = fmaxf(mx, __shfl_xor(mx, o, 64));
  float p = (lane < 41) ? __expf(v - mx) : 0.f;
  float sum = p;
#pragma unroll
  for (int o = 32; o >= 1; o >>= 1) sum += __shfl_xor(sum, o, 64);
  if (lane < 41) out[(size_t)d * 41 + lane] = v - mx - logf(sum);
}

// ---------------- host launch ----------------
extern "C" void kernel_launch(void* const* d_in, const int* in_sizes, int n_in,
                              void* d_out, int out_size, void* d_ws, size_t ws_size,
                              hipStream_t stream) {
  const float* x = (const float*)d_in[0];
  const int* ei1 = (const int*)d_in[1];
  const int* ei2 = (const int*)d_in[2];
  const float* W1 = (const float*)d_in[5];
  const float* att_src1 = (const float*)d_in[6];
  const float* att_dst1 = (const float*)d_in[7];
  const float* b1 = (const float*)d_in[8];
  const float* W2 = (const float*)d_in[9];
  const float* att_src2 = (const float*)d_in[10];
  const float* att_dst2 = (const float*)d_in[11];
  const float* b2 = (const float*)d_in[12];
  float* out = (float*)d_out;

  const int E1 = in_sizes[1] / 2;
  const int E2 = in_sizes[2] / 2;
  const int* src1 = ei1;
  const int* dst1 = ei1 + E1;
  const int* src2 = ei2;
  const int* dst2 = ei2 + E2;

  // workspace bump allocator (256B aligned)
  char* w = (char*)d_ws;
  size_t off = 0;
  auto alloc = [&](size_t bytes) {
    void* p = w + off;
    off += (bytes + 255) & ~(size_t)255;
    return p;
  };
  unsigned short* Wt  = (unsigned short*)alloc((size_t)HCv * KPADv * 2);
  unsigned short* H   = (unsigned short*)alloc((size_t)N0v * HCv * 2);
  float* as1 = (float*)alloc((size_t)N0v * 8 * 4);
  float* ad1 = (float*)alloc((size_t)N1v * 8 * 4);
  int* deg1  = (int*)alloc((size_t)N1v * 4);
  int* rs1   = (int*)alloc((size_t)(N1v + 1) * 4);
  int* cur1  = (int*)alloc((size_t)N1v * 4);
  int* es1   = (int*)alloc((size_t)E1 * 4);
  float* h1  = (float*)alloc((size_t)N1v * HCv * 4);
  float* g   = (float*)alloc((size_t)N1v * 41 * 4);
  float* as2 = (float*)alloc((size_t)N1v * 4);
  float* ad2 = (float*)alloc((size_t)N1v * 4);
  int* deg2  = (int*)alloc((size_t)N2v * 4);
  int* rs2   = (int*)alloc((size_t)(N2v + 1) * 4);
  int* cur2  = (int*)alloc((size_t)N2v * 4);
  int* es2   = (int*)alloc((size_t)E2 * 4);
  (void)ws_size; (void)n_in; (void)out_size;

  hipMemsetAsync(deg1, 0, (size_t)N1v * 4, stream);
  hipMemsetAsync(deg2, 0, (size_t)N2v * 4, stream);

  k_transposeW1<<<(HCv * KPADv + 255) / 256, 256, 0, stream>>>(W1, Wt);
  k_gemm1<<<N0v / 64, 256, 0, stream>>>(x, Wt, H);
  k_dots1<<<(N0v + 255) / 256, 256, 0, stream>>>(H, att_src1, att_dst1, as1, ad1);

  k_count<<<(E1 + 255) / 256, 256, 0, stream>>>(dst1, E1, deg1);
  k_scan<<<1, 1024, 0, stream>>>(deg1, rs1, cur1, N1v);
  k_scatter<<<(E1 + 255) / 256, 256, 0, stream>>>(src1, dst1, E1, cur1, es1);
  k_attn1<<<N1v / 4, 256, 0, stream>>>(as1, ad1, rs1, es1, H, b1, h1);

  k_l2feat<<<(N1v + 255) / 256, 256, 0, stream>>>(h1, W2, att_src2, att_dst2, g, as2, ad2);

  k_count<<<(E2 + 255) / 256, 256, 0, stream>>>(dst2, E2, deg2);
  k_scan<<<1, 1024, 0, stream>>>(deg2, rs2, cur2, N2v);
  k_scatter<<<(E2 + 255) / 256, 256, 0, stream>>>(src2, dst2, E2, cur2, es2);
  k_attn2<<<N2v / 4, 256, 0, stream>>>(as2, ad2, rs2, es2, g, b2, out);
}

// Round 3
// 277.933 us; speedup vs baseline: 1.0309x; 1.0309x over previous
//
#include <hip/hip_runtime.h>
#include <math.h>

typedef short bf16x8 __attribute__((ext_vector_type(8)));
typedef float f32x4 __attribute__((ext_vector_type(4)));

#define N0v 120000
#define N1v 12000
#define N2v 1024
#define F_INv 602
#define KPADv 608
#define HCv 64
#define NCLSv 41
#define NEGv 0.2f

__device__ __forceinline__ float b2f(unsigned short u) {
  return __uint_as_float(((unsigned int)u) << 16);
}
__device__ __forceinline__ unsigned short f2b(float f) {
  unsigned int u = __float_as_uint(f);
  u += 0x7fffu + ((u >> 16) & 1u);
  return (unsigned short)(u >> 16);
}
__device__ __forceinline__ float leaky(float v) {
  return v > 0.f ? v : NEGv * v;
}

// ---------------- zero helper (replaces 2 memsets) ----------------
__global__ void k_zero(int* __restrict__ a, int na, int* __restrict__ b, int nb) {
  int i = blockIdx.x * 256 + threadIdx.x;
  if (i < na) a[i] = 0;
  if (i < nb) b[i] = 0;
}

// ---------------- W1 transpose+convert: Wt[n][kpad] = bf16(W1[k][n]) ----------------
__global__ void k_transposeW1(const float* __restrict__ W1,
                              unsigned short* __restrict__ Wt) {
  int idx = blockIdx.x * 256 + threadIdx.x;
  if (idx >= HCv * KPADv) return;
  int n = idx / KPADv, k = idx % KPADv;
  Wt[idx] = (k < F_INv) ? f2b(W1[k * HCv + n]) : (unsigned short)0;
}

// ---------------- GEMM: H = x @ W1, fused att dots (as1, ad1) ----------------
// 512 threads, BM=128, pipelined: load kt+1 (f32 regs) under MFMA of kt.
__global__ __launch_bounds__(512) void k_gemm1(const float* __restrict__ x,
                                               const unsigned short* __restrict__ Wt,
                                               unsigned short* __restrict__ H,
                                               float* __restrict__ as1,
                                               float* __restrict__ ad1,
                                               const float* __restrict__ att_s,
                                               const float* __restrict__ att_d) {
  __shared__ unsigned short As[128][40];  // 80B row stride
  __shared__ unsigned short Bs[64][40];
  __shared__ float sAtt[128];
  const int tid = threadIdx.x;
  const int wave = tid >> 6, lane = tid & 63;
  const int c15 = lane & 15;
  const int block_row = blockIdx.x * 128;
  const int seg = tid & 3;
  const int ar = tid >> 2;                       // 0..127 (A staging row)
  const int ra = min(block_row + ar, N0v - 1);   // clamp OOB rows (stores guarded)

  if (tid < 64) sAtt[tid] = att_s[tid];
  else if (tid < 128) sAtt[tid] = att_d[tid - 64];

  f32x4 acc[4];
#pragma unroll
  for (int n = 0; n < 4; ++n) acc[n] = (f32x4){0.f, 0.f, 0.f, 0.f};

  float fa[8];
  uint4 bv;

  auto loadA = [&](int kt) {
    const int k = kt * 32 + seg * 8;
    const float* sa = x + (size_t)ra * F_INv + k;
    if (k + 8 <= F_INv) {
#pragma unroll
      for (int q = 0; q < 4; ++q) {
        float2 t = *reinterpret_cast<const float2*>(sa + q * 2);
        fa[2 * q] = t.x;
        fa[2 * q + 1] = t.y;
      }
    } else {
#pragma unroll
      for (int q = 0; q < 8; ++q) fa[q] = (k + q < F_INv) ? sa[q] : 0.f;
    }
  };
  auto loadB = [&](int kt) {
    if (tid < 256)
      bv = *reinterpret_cast<const uint4*>(Wt + (size_t)(tid >> 2) * KPADv + kt * 32 + seg * 8);
  };

  loadA(0);
  loadB(0);

  for (int kt = 0; kt < 19; ++kt) {
    __syncthreads();  // prior-iter LDS reads complete
    {
      unsigned int av[4];
#pragma unroll
      for (int q = 0; q < 4; ++q)
        av[q] = (unsigned int)f2b(fa[2 * q]) | ((unsigned int)f2b(fa[2 * q + 1]) << 16);
      *reinterpret_cast<uint4*>(&As[ar][seg * 8]) = make_uint4(av[0], av[1], av[2], av[3]);
      if (tid < 256) *reinterpret_cast<uint4*>(&Bs[tid >> 2][seg * 8]) = bv;
    }
    __syncthreads();
    if (kt + 1 < 19) {  // prefetch next tile under MFMA
      loadA(kt + 1);
      loadB(kt + 1);
    }
    const int arow = wave * 16 + c15;
    const int kb = (lane >> 4) * 8;
    bf16x8 a = *reinterpret_cast<const bf16x8*>(&As[arow][kb]);
#pragma unroll
    for (int n = 0; n < 4; ++n) {
      bf16x8 b = *reinterpret_cast<const bf16x8*>(&Bs[n * 16 + c15][kb]);
      acc[n] = __builtin_amdgcn_mfma_f32_16x16x32_bf16(a, b, acc[n], 0, 0, 0);
    }
  }

  // epilogue: col = n*16 + c15, row = wave*16 + (lane>>4)*4 + j; fused att dots
  float attS[4], attD[4];
#pragma unroll
  for (int n = 0; n < 4; ++n) {
    attS[n] = sAtt[n * 16 + c15];
    attD[n] = sAtt[64 + n * 16 + c15];
  }
#pragma unroll
  for (int j = 0; j < 4; ++j) {
    int row = block_row + wave * 16 + (lane >> 4) * 4 + j;
    bool rok = row < N0v;
#pragma unroll
    for (int n = 0; n < 4; ++n) {
      if (rok) H[(size_t)row * HCv + n * 16 + c15] = f2b(acc[n][j]);
      float ps = acc[n][j] * attS[n];
      float pd = acc[n][j] * attD[n];
      ps += __shfl_xor(ps, 1, 64);
      ps += __shfl_xor(ps, 2, 64);
      ps += __shfl_xor(ps, 4, 64);
      pd += __shfl_xor(pd, 1, 64);
      pd += __shfl_xor(pd, 2, 64);
      pd += __shfl_xor(pd, 4, 64);
      if (rok && ((c15 & 7) == 0)) {
        int hd = n * 2 + (c15 >> 3);  // head = col>>3
        as1[(size_t)row * 8 + hd] = ps;
        if (row < N1v) ad1[(size_t)row * 8 + hd] = pd;
      }
    }
  }
}

// ---------------- CSR build ----------------
__global__ void k_count(const int* __restrict__ dst, int E, int* __restrict__ deg) {
  int e = blockIdx.x * 256 + threadIdx.x;
  if (e < E) atomicAdd(&deg[dst[e]], 1);
}

// single block, 1024 threads, ELT elems/thread (compile-time), few barriers
template <int ELT>
__global__ __launch_bounds__(1024) void k_scan(const int* __restrict__ deg,
                                               int* __restrict__ rs,
                                               int* __restrict__ cur, int n) {
  __shared__ int wsum[16];
  const int t = threadIdx.x, lane = t & 63, wid = t >> 6;
  int vals[ELT];
  int tot = 0;
#pragma unroll
  for (int e = 0; e < ELT; ++e) {
    int i = t * ELT + e;
    int v = (i < n) ? deg[i] : 0;
    vals[e] = v;
    tot += v;
  }
  int s = tot;  // inclusive wave scan
#pragma unroll
  for (int off = 1; off < 64; off <<= 1) {
    int u = __shfl_up(s, off, 64);
    if (lane >= off) s += u;
  }
  if (lane == 63) wsum[wid] = s;
  __syncthreads();
  if (t < 16) {
    int w = wsum[t];
#pragma unroll
    for (int off = 1; off < 16; off <<= 1) {
      int u = __shfl_up(w, off, 64);
      if (t >= off) w += u;
    }
    wsum[t] = w;  // inclusive wave totals
  }
  __syncthreads();
  int woff = (wid == 0) ? 0 : wsum[wid - 1];
  int run = woff + s - tot;  // exclusive prefix of this thread's chunk
#pragma unroll
  for (int e = 0; e < ELT; ++e) {
    int i = t * ELT + e;
    if (i < n) {
      rs[i] = run;
      cur[i] = run;
    }
    run += vals[e];
  }
  if (t == 1023) rs[n] = run;  // grand total
}

__global__ void k_scatter(const int* __restrict__ src, const int* __restrict__ dst, int E,
                          int* __restrict__ cur, int* __restrict__ esrc) {
  int e = blockIdx.x * 256 + threadIdx.x;
  if (e < E) {
    int p = atomicAdd(&cur[dst[e]], 1);
    esrc[p] = src[e];
  }
}

// ---------------- layer-1 attention: one wave per dst, online softmax ----------------
__global__ __launch_bounds__(256) void k_attn1(const float* __restrict__ as1,
                                               const float* __restrict__ ad1,
                                               const int* __restrict__ rs,
                                               const int* __restrict__ esrc,
                                               const unsigned short* __restrict__ H,
                                               const float* __restrict__ b1,
                                               float* __restrict__ h1) {
  int wave = threadIdx.x >> 6, lane = threadIdx.x & 63;
  int d = blockIdx.x * 4 + wave;
  if (d >= N1v) return;
  int h = lane >> 3;
  int beg = rs[d], end = rs[d + 1];
  float adh = ad1[(size_t)d * 8 + h];
  float m = leaky(as1[(size_t)d * 8 + h] + adh);  // self-loop term, e=1
  float ssum = 1.f;
  float acc = b2f(H[(size_t)d * HCv + lane]);
  for (int p = beg; p < end; ++p) {
    int s = esrc[p];
    float a = leaky(as1[(size_t)s * 8 + h] + adh);
    float hv = b2f(H[(size_t)s * HCv + lane]);
    float mn = fmaxf(m, a);
    float sc = __expf(m - mn);
    float e = __expf(a - mn);
    ssum = ssum * sc + e;
    acc = acc * sc + e * hv;
    m = mn;
  }
  float o = acc / ssum + b1[lane];
  o = o > 0.f ? o : expm1f(o);  // ELU
  h1[(size_t)d * HCv + lane] = o;
}

// ---------------- layer-2 features: g = h1 @ W2, + attention dots ----------------
__global__ __launch_bounds__(256) void k_l2feat(const float* __restrict__ h1,
                                                const float* __restrict__ W2,
                                                const float* __restrict__ a_s,
                                                const float* __restrict__ a_d,
                                                float* __restrict__ g,
                                                float* __restrict__ as2,
                                                float* __restrict__ ad2) {
  __shared__ float w[64 * 41];
  __shared__ float vs[41], vd[41];
  int tid = threadIdx.x;
  for (int idx = tid; idx < 64 * 41; idx += 256) w[idx] = W2[idx];
  if (tid < 41) {
    vs[tid] = a_s[tid];
    vd[tid] = a_d[tid];
  }
  __syncthreads();
  int i = blockIdx.x * 256 + tid;
  if (i >= N1v) return;
  float r[64];
  const float4* hp = reinterpret_cast<const float4*>(h1 + (size_t)i * HCv);
#pragma unroll
  for (int q = 0; q < 16; ++q) {
    float4 t = hp[q];
    r[q * 4 + 0] = t.x; r[q * 4 + 1] = t.y; r[q * 4 + 2] = t.z; r[q * 4 + 3] = t.w;
  }
  float sa = 0.f, da = 0.f;
  for (int c = 0; c < 41; ++c) {
    float a = 0.f;
#pragma unroll
    for (int k = 0; k < 64; ++k) a += r[k] * w[k * 41 + c];
    g[(size_t)i * 41 + c] = a;
    sa += a * vs[c];
    da += a * vd[c];
  }
  as2[i] = sa;
  ad2[i] = da;
}

// ---------------- layer-2 attention + log_softmax ----------------
__global__ __launch_bounds__(256) void k_attn2(const float* __restrict__ as2,
                                               const float* __restrict__ ad2,
                                               const int* __restrict__ rs,
                                               const int* __restrict__ esrc,
                                               const float* __restrict__ g,
                                               const float* __restrict__ b2,
                                               float* __restrict__ out) {
  int wave = threadIdx.x >> 6, lane = threadIdx.x & 63;
  int d = blockIdx.x * 4 + wave;
  if (d >= N2v) return;
  int beg = rs[d], end = rs[d + 1];
  float ad = ad2[d];
  float a_self = leaky(as2[d] + ad);
  float m = a_self;
  for (int p = beg; p < end; ++p) m = fmaxf(m, leaky(as2[esrc[p]] + ad));
  float ssum, acc;
  {
    float e = __expf(a_self - m);
    ssum = e;
    acc = (lane < 41) ? e * g[(size_t)d * 41 + lane] : 0.f;
  }
  for (int p = beg; p < end; ++p) {
    int s = esrc[p];
    float e = __expf(leaky(as2[s] + ad) - m);
    ssum += e;
    if (lane < 41) acc += e * g[(size_t)s * 41 + lane];
  }
  float logit = acc / ssum + ((lane < 41) ? b2[lane] : 0.f);
  float v = (lane < 41) ? logit : -INFINITY;
  float mx = v;
#pragma unroll
  for (int o = 32; o >= 1; o >>= 1) mx = fmaxf(mx, __shfl_xor(mx, o, 64));
  float p = (lane < 41) ? __expf(v - mx) : 0.f;
  float sum = p;
#pragma unroll
  for (int o = 32; o >= 1; o >>= 1) sum += __shfl_xor(sum, o, 64);
  if (lane < 41) out[(size_t)d * 41 + lane] = v - mx - logf(sum);
}

// ---------------- host launch ----------------
extern "C" void kernel_launch(void* const* d_in, const int* in_sizes, int n_in,
                              void* d_out, int out_size, void* d_ws, size_t ws_size,
                              hipStream_t stream) {
  const float* x = (const float*)d_in[0];
  const int* ei1 = (const int*)d_in[1];
  const int* ei2 = (const int*)d_in[2];
  const float* W1 = (const float*)d_in[5];
  const float* att_src1 = (const float*)d_in[6];
  const float* att_dst1 = (const float*)d_in[7];
  const float* b1 = (const float*)d_in[8];
  const float* W2 = (const float*)d_in[9];
  const float* att_src2 = (const float*)d_in[10];
  const float* att_dst2 = (const float*)d_in[11];
  const float* b2 = (const float*)d_in[12];
  float* out = (float*)d_out;

  const int E1 = in_sizes[1] / 2;
  const int E2 = in_sizes[2] / 2;
  const int* src1 = ei1;
  const int* dst1 = ei1 + E1;
  const int* src2 = ei2;
  const int* dst2 = ei2 + E2;

  char* w = (char*)d_ws;
  size_t off = 0;
  auto alloc = [&](size_t bytes) {
    void* p = w + off;
    off += (bytes + 255) & ~(size_t)255;
    return p;
  };
  unsigned short* Wt  = (unsigned short*)alloc((size_t)HCv * KPADv * 2);
  unsigned short* H   = (unsigned short*)alloc((size_t)N0v * HCv * 2);
  float* as1 = (float*)alloc((size_t)N0v * 8 * 4);
  float* ad1 = (float*)alloc((size_t)N1v * 8 * 4);
  int* deg1  = (int*)alloc((size_t)N1v * 4);
  int* rs1   = (int*)alloc((size_t)(N1v + 1) * 4);
  int* cur1  = (int*)alloc((size_t)N1v * 4);
  int* es1   = (int*)alloc((size_t)E1 * 4);
  float* h1  = (float*)alloc((size_t)N1v * HCv * 4);
  float* g   = (float*)alloc((size_t)N1v * 41 * 4);
  float* as2 = (float*)alloc((size_t)N1v * 4);
  float* ad2 = (float*)alloc((size_t)N1v * 4);
  int* deg2  = (int*)alloc((size_t)N2v * 4);
  int* rs2   = (int*)alloc((size_t)(N2v + 1) * 4);
  int* cur2  = (int*)alloc((size_t)N2v * 4);
  int* es2   = (int*)alloc((size_t)E2 * 4);
  (void)ws_size; (void)n_in; (void)out_size;

  k_zero<<<(N1v + 255) / 256, 256, 0, stream>>>(deg1, N1v, deg2, N2v);
  k_transposeW1<<<(HCv * KPADv + 255) / 256, 256, 0, stream>>>(W1, Wt);
  k_gemm1<<<(N0v + 127) / 128, 512, 0, stream>>>(x, Wt, H, as1, ad1, att_src1, att_dst1);

  k_count<<<(E1 + 255) / 256, 256, 0, stream>>>(dst1, E1, deg1);
  k_scan<12><<<1, 1024, 0, stream>>>(deg1, rs1, cur1, N1v);
  k_scatter<<<(E1 + 255) / 256, 256, 0, stream>>>(src1, dst1, E1, cur1, es1);
  k_attn1<<<N1v / 4, 256, 0, stream>>>(as1, ad1, rs1, es1, H, b1, h1);

  k_l2feat<<<(N1v + 255) / 256, 256, 0, stream>>>(h1, W2, att_src2, att_dst2, g, as2, ad2);

  k_count<<<(E2 + 255) / 256, 256, 0, stream>>>(dst2, E2, deg2);
  k_scan<1><<<1, 1024, 0, stream>>>(deg2, rs2, cur2, N2v);
  k_scatter<<<(E2 + 255) / 256, 256, 0, stream>>>(src2, dst2, E2, cur2, es2);
  k_attn2<<<N2v / 4, 256, 0, stream>>>(as2, ad2, rs2, es2, g, b2, out);
}

// Round 4
// 231.820 us; speedup vs baseline: 1.2360x; 1.1989x over previous
//
#include <hip/hip_runtime.h>
#include <hip/hip_bf16.h>
#include <math.h>

typedef short bf16x8 __attribute__((ext_vector_type(8)));
typedef float f32x4 __attribute__((ext_vector_type(4)));

#define N0v 120000
#define N1v 12000
#define N2v 1024
#define F_INv 602
#define KPADv 608
#define HCv 64
#define NCLSv 41
#define NEGv 0.2f

__device__ __forceinline__ float b2f(unsigned short u) {
  return __uint_as_float(((unsigned int)u) << 16);
}
__device__ __forceinline__ unsigned short f2b(float f) {
  unsigned int u = __float_as_uint(f);
  u += 0x7fffu + ((u >> 16) & 1u);
  return (unsigned short)(u >> 16);
}
__device__ __forceinline__ unsigned int pk2(float lo, float hi) {
  __hip_bfloat162 h = __float22bfloat162_rn(make_float2(lo, hi));
  unsigned int u;
  __builtin_memcpy(&u, &h, 4);
  return u;
}
__device__ __forceinline__ float leaky(float v) {
  return v > 0.f ? v : NEGv * v;
}

// ---------------- prep: W1 transpose+convert to Wt[64][608] bf16, zero deg arrays ----------------
__global__ void k_prep(const float* __restrict__ W1, unsigned short* __restrict__ Wt,
                       int* __restrict__ deg1, int* __restrict__ deg2) {
  int idx = blockIdx.x * 256 + threadIdx.x;
  if (idx < HCv * KPADv) {
    int n = idx / KPADv, k = idx % KPADv;
    Wt[idx] = (k < F_INv) ? f2b(W1[k * HCv + n]) : (unsigned short)0;
  }
  if (idx < N1v) deg1[idx] = 0;
  if (idx < N2v) deg2[idx] = 0;
}

// ---------------- GEMM: H = x @ W1 + fused att dots. B in LDS (2 K-halves), A global->reg, no per-step barriers ----------------
__global__ __launch_bounds__(512, 4) void k_gemm1(const float* __restrict__ x,
                                                  const unsigned short* __restrict__ Wt,
                                                  unsigned short* __restrict__ H,
                                                  float* __restrict__ as1,
                                                  float* __restrict__ ad1,
                                                  const float* __restrict__ att_s,
                                                  const float* __restrict__ att_d) {
  __shared__ unsigned short Bs[64][328];  // 656B stride: 164 dwords % 32 = 4 -> 2-way (free)
  __shared__ float sAtt[128];
  const int tid = threadIdx.x;
  const int wave = tid >> 6, lane = tid & 63;
  const int c15 = lane & 15, kseg = lane >> 4;
  const int block_row = blockIdx.x * 128;
  const int myrow = block_row + wave * 16 + c15;
  const float* rowp = x + (size_t)min(myrow, N0v - 1) * F_INv;

  if (tid < 128) sAtt[tid] = (tid < 64) ? att_s[tid] : att_d[tid - 64];

  auto stage = [&](int kofs, int nc8) {  // copy Wt[:, kofs : kofs+nc8*8] into Bs
    int chunks = 64 * nc8;
    for (int i = tid; i < chunks; i += 512) {
      int rr = i / nc8, cc = (i % nc8) * 8;
      *reinterpret_cast<uint4*>(&Bs[rr][cc]) =
          *reinterpret_cast<const uint4*>(Wt + (size_t)rr * KPADv + kofs + cc);
    }
  };

  f32x4 acc[4];
#pragma unroll
  for (int n = 0; n < 4; ++n) acc[n] = (f32x4){0.f, 0.f, 0.f, 0.f};

  float cur[8], nxt[8];
  auto loadA = [&](int kt, float (&f)[8]) {
    const int kb = kt * 32 + kseg * 8;
    const float* p = rowp + kb;
    if (kb + 8 <= F_INv) {
#pragma unroll
      for (int q = 0; q < 4; ++q) {
        float2 t = *reinterpret_cast<const float2*>(p + 2 * q);
        f[2 * q] = t.x;
        f[2 * q + 1] = t.y;
      }
    } else {  // only kt=18, kseg=3: k=600..607, load 600,601, rest 0 (B pad is 0 there)
      float2 t = *reinterpret_cast<const float2*>(p);
      f[0] = t.x;
      f[1] = t.y;
#pragma unroll
      for (int q = 2; q < 8; ++q) f[q] = 0.f;
    }
  };
  auto compute = [&](int kt) {
    union {
      unsigned int u[4];
      bf16x8 v;
    } af;
#pragma unroll
    for (int q = 0; q < 4; ++q) af.u[q] = pk2(cur[2 * q], cur[2 * q + 1]);
    const int kk = (kt < 10 ? kt * 32 : kt * 32 - 320) + kseg * 8;
#pragma unroll
    for (int n = 0; n < 4; ++n) {
      bf16x8 b = *reinterpret_cast<const bf16x8*>(&Bs[n * 16 + c15][kk]);
      acc[n] = __builtin_amdgcn_mfma_f32_16x16x32_bf16(af.v, b, acc[n], 0, 0, 0);
    }
  };

  stage(0, 40);  // k 0..319
  loadA(0, cur);
  __syncthreads();
#pragma unroll
  for (int kt = 0; kt < 10; ++kt) {
    loadA(kt + 1, nxt);  // A-loads independent of Bs
    compute(kt);
#pragma unroll
    for (int q = 0; q < 8; ++q) cur[q] = nxt[q];
  }
  __syncthreads();   // all waves done reading half 0
  stage(320, 36);    // k 320..607
  __syncthreads();
#pragma unroll
  for (int kt = 10; kt < 19; ++kt) {
    if (kt < 18) loadA(kt + 1, nxt);
    compute(kt);
    if (kt < 18) {
#pragma unroll
      for (int q = 0; q < 8; ++q) cur[q] = nxt[q];
    }
  }

  // epilogue: col = n*16 + c15, row = wave*16 + kseg*4 + j; fused att dots
  float attS[4], attD[4];
#pragma unroll
  for (int n = 0; n < 4; ++n) {
    attS[n] = sAtt[n * 16 + c15];
    attD[n] = sAtt[64 + n * 16 + c15];
  }
#pragma unroll
  for (int j = 0; j < 4; ++j) {
    int row = block_row + wave * 16 + kseg * 4 + j;
    bool rok = row < N0v;
#pragma unroll
    for (int n = 0; n < 4; ++n) {
      if (rok) H[(size_t)row * HCv + n * 16 + c15] = f2b(acc[n][j]);
      float ps = acc[n][j] * attS[n];
      float pd = acc[n][j] * attD[n];
      ps += __shfl_xor(ps, 1, 64);
      ps += __shfl_xor(ps, 2, 64);
      ps += __shfl_xor(ps, 4, 64);
      pd += __shfl_xor(pd, 1, 64);
      pd += __shfl_xor(pd, 2, 64);
      pd += __shfl_xor(pd, 4, 64);
      if (rok && ((c15 & 7) == 0)) {
        int hd = n * 2 + (c15 >> 3);
        as1[(size_t)row * 8 + hd] = ps;
        if (row < N1v) ad1[(size_t)row * 8 + hd] = pd;
      }
    }
  }
}

// ---------------- merged CSR build (both graphs) ----------------
__global__ void k_count2x(const int* __restrict__ dst1, int E1, int* __restrict__ deg1,
                          const int* __restrict__ dst2, int E2, int* __restrict__ deg2) {
  int e = blockIdx.x * 256 + threadIdx.x;
  if (e < E1) atomicAdd(&deg1[dst1[e]], 1);
  if (e < E2) atomicAdd(&deg2[dst2[e]], 1);
}

template <int ELT>
__device__ __forceinline__ void scan_body(const int* __restrict__ deg, int* __restrict__ rs,
                                          int* __restrict__ cur, int n) {
  __shared__ int wsum[16];
  const int t = threadIdx.x, lane = t & 63, wid = t >> 6;
  int vals[ELT];
  int tot = 0;
#pragma unroll
  for (int e = 0; e < ELT; ++e) {
    int i = t * ELT + e;
    int v = (i < n) ? deg[i] : 0;
    vals[e] = v;
    tot += v;
  }
  int s = tot;
#pragma unroll
  for (int off = 1; off < 64; off <<= 1) {
    int u = __shfl_up(s, off, 64);
    if (lane >= off) s += u;
  }
  if (lane == 63) wsum[wid] = s;
  __syncthreads();
  if (t < 16) {
    int w = wsum[t];
#pragma unroll
    for (int off = 1; off < 16; off <<= 1) {
      int u = __shfl_up(w, off, 64);
      if (t >= off) w += u;
    }
    wsum[t] = w;
  }
  __syncthreads();
  int woff = (wid == 0) ? 0 : wsum[wid - 1];
  int run = woff + s - tot;
#pragma unroll
  for (int e = 0; e < ELT; ++e) {
    int i = t * ELT + e;
    if (i < n) {
      rs[i] = run;
      cur[i] = run;
    }
    run += vals[e];
  }
  if (t == 1023) rs[n] = run;
}

__global__ __launch_bounds__(1024) void k_scan2x(const int* __restrict__ deg1, int* __restrict__ rs1,
                                                 int* __restrict__ cur1, int n1,
                                                 const int* __restrict__ deg2, int* __restrict__ rs2,
                                                 int* __restrict__ cur2, int n2) {
  if (blockIdx.x == 0)
    scan_body<12>(deg1, rs1, cur1, n1);
  else
    scan_body<12>(deg2, rs2, cur2, n2);
}

__global__ void k_scatter2x(const int* __restrict__ src1, const int* __restrict__ dst1, int E1,
                            int* __restrict__ cur1, int* __restrict__ es1,
                            const int* __restrict__ src2, const int* __restrict__ dst2, int E2,
                            int* __restrict__ cur2, int* __restrict__ es2) {
  int e = blockIdx.x * 256 + threadIdx.x;
  if (e < E1) {
    int p = atomicAdd(&cur1[dst1[e]], 1);
    es1[p] = src1[e];
  }
  if (e < E2) {
    int p = atomicAdd(&cur2[dst2[e]], 1);
    es2[p] = src2[e];
  }
}

// ---------------- layer-1 attention: one wave per dst, online softmax ----------------
__global__ __launch_bounds__(256) void k_attn1(const float* __restrict__ as1,
                                               const float* __restrict__ ad1,
                                               const int* __restrict__ rs,
                                               const int* __restrict__ esrc,
                                               const unsigned short* __restrict__ H,
                                               const float* __restrict__ b1,
                                               float* __restrict__ h1) {
  int wave = threadIdx.x >> 6, lane = threadIdx.x & 63;
  int d = blockIdx.x * 4 + wave;
  if (d >= N1v) return;
  int h = lane >> 3;
  int beg = rs[d], end = rs[d + 1];
  float adh = ad1[(size_t)d * 8 + h];
  float m = leaky(as1[(size_t)d * 8 + h] + adh);  // self-loop term, e=1
  float ssum = 1.f;
  float acc = b2f(H[(size_t)d * HCv + lane]);
  for (int p = beg; p < end; ++p) {
    int s = esrc[p];
    float a = leaky(as1[(size_t)s * 8 + h] + adh);
    float hv = b2f(H[(size_t)s * HCv + lane]);
    float mn = fmaxf(m, a);
    float sc = __expf(m - mn);
    float e = __expf(a - mn);
    ssum = ssum * sc + e;
    acc = acc * sc + e * hv;
    m = mn;
  }
  float o = acc / ssum + b1[lane];
  o = o > 0.f ? o : expm1f(o);  // ELU
  h1[(size_t)d * HCv + lane] = o;
}

// ---------------- layer-2 features: g = h1 @ W2, + attention dots ----------------
__global__ __launch_bounds__(256) void k_l2feat(const float* __restrict__ h1,
                                                const float* __restrict__ W2,
                                                const float* __restrict__ a_s,
                                                const float* __restrict__ a_d,
                                                float* __restrict__ g,
                                                float* __restrict__ as2,
                                                float* __restrict__ ad2) {
  __shared__ float w[64 * 41];
  __shared__ float vs[41], vd[41];
  int tid = threadIdx.x;
  for (int idx = tid; idx < 64 * 41; idx += 256) w[idx] = W2[idx];
  if (tid < 41) {
    vs[tid] = a_s[tid];
    vd[tid] = a_d[tid];
  }
  __syncthreads();
  int i = blockIdx.x * 256 + tid;
  if (i >= N1v) return;
  float r[64];
  const float4* hp = reinterpret_cast<const float4*>(h1 + (size_t)i * HCv);
#pragma unroll
  for (int q = 0; q < 16; ++q) {
    float4 t = hp[q];
    r[q * 4 + 0] = t.x; r[q * 4 + 1] = t.y; r[q * 4 + 2] = t.z; r[q * 4 + 3] = t.w;
  }
  float sa = 0.f, da = 0.f;
  for (int c = 0; c < 41; ++c) {
    float a = 0.f;
#pragma unroll
    for (int k = 0; k < 64; ++k) a += r[k] * w[k * 41 + c];
    g[(size_t)i * 41 + c] = a;
    sa += a * vs[c];
    da += a * vd[c];
  }
  as2[i] = sa;
  ad2[i] = da;
}

// ---------------- layer-2 attention + log_softmax ----------------
__global__ __launch_bounds__(256) void k_attn2(const float* __restrict__ as2,
                                               const float* __restrict__ ad2,
                                               const int* __restrict__ rs,
                                               const int* __restrict__ esrc,
                                               const float* __restrict__ g,
                                               const float* __restrict__ b2,
                                               float* __restrict__ out) {
  int wave = threadIdx.x >> 6, lane = threadIdx.x & 63;
  int d = blockIdx.x * 4 + wave;
  if (d >= N2v) return;
  int beg = rs[d], end = rs[d + 1];
  float ad = ad2[d];
  float a_self = leaky(as2[d] + ad);
  float m = a_self;
  for (int p = beg; p < end; ++p) m = fmaxf(m, leaky(as2[esrc[p]] + ad));
  float ssum, acc;
  {
    float e = __expf(a_self - m);
    ssum = e;
    acc = (lane < 41) ? e * g[(size_t)d * 41 + lane] : 0.f;
  }
  for (int p = beg; p < end; ++p) {
    int s = esrc[p];
    float e = __expf(leaky(as2[s] + ad) - m);
    ssum += e;
    if (lane < 41) acc += e * g[(size_t)s * 41 + lane];
  }
  float logit = acc / ssum + ((lane < 41) ? b2[lane] : 0.f);
  float v = (lane < 41) ? logit : -INFINITY;
  float mx = v;
#pragma unroll
  for (int o = 32; o >= 1; o >>= 1) mx = fmaxf(mx, __shfl_xor(mx, o, 64));
  float p = (lane < 41) ? __expf(v - mx) : 0.f;
  float sum = p;
#pragma unroll
  for (int o = 32; o >= 1; o >>= 1) sum += __shfl_xor(sum, o, 64);
  if (lane < 41) out[(size_t)d * 41 + lane] = v - mx - logf(sum);
}

// ---------------- host launch ----------------
extern "C" void kernel_launch(void* const* d_in, const int* in_sizes, int n_in,
                              void* d_out, int out_size, void* d_ws, size_t ws_size,
                              hipStream_t stream) {
  const float* x = (const float*)d_in[0];
  const int* ei1 = (const int*)d_in[1];
  const int* ei2 = (const int*)d_in[2];
  const float* W1 = (const float*)d_in[5];
  const float* att_src1 = (const float*)d_in[6];
  const float* att_dst1 = (const float*)d_in[7];
  const float* b1 = (const float*)d_in[8];
  const float* W2 = (const float*)d_in[9];
  const float* att_src2 = (const float*)d_in[10];
  const float* att_dst2 = (const float*)d_in[11];
  const float* b2 = (const float*)d_in[12];
  float* out = (float*)d_out;

  const int E1 = in_sizes[1] / 2;
  const int E2 = in_sizes[2] / 2;
  const int* src1 = ei1;
  const int* dst1 = ei1 + E1;
  const int* src2 = ei2;
  const int* dst2 = ei2 + E2;

  char* w = (char*)d_ws;
  size_t off = 0;
  auto alloc = [&](size_t bytes) {
    void* p = w + off;
    off += (bytes + 255) & ~(size_t)255;
    return p;
  };
  unsigned short* Wt  = (unsigned short*)alloc((size_t)HCv * KPADv * 2);
  unsigned short* H   = (unsigned short*)alloc((size_t)N0v * HCv * 2);
  float* as1 = (float*)alloc((size_t)N0v * 8 * 4);
  float* ad1 = (float*)alloc((size_t)N1v * 8 * 4);
  int* deg1  = (int*)alloc((size_t)N1v * 4);
  int* rs1   = (int*)alloc((size_t)(N1v + 1) * 4);
  int* cur1  = (int*)alloc((size_t)N1v * 4);
  int* es1   = (int*)alloc((size_t)E1 * 4);
  float* h1  = (float*)alloc((size_t)N1v * HCv * 4);
  float* g   = (float*)alloc((size_t)N1v * 41 * 4);
  float* as2 = (float*)alloc((size_t)N1v * 4);
  float* ad2 = (float*)alloc((size_t)N1v * 4);
  int* deg2  = (int*)alloc((size_t)N2v * 4);
  int* rs2   = (int*)alloc((size_t)(N2v + 1) * 4);
  int* cur2  = (int*)alloc((size_t)N2v * 4);
  int* es2   = (int*)alloc((size_t)E2 * 4);
  (void)ws_size; (void)n_in; (void)out_size;

  k_prep<<<(HCv * KPADv + 255) / 256, 256, 0, stream>>>(W1, Wt, deg1, deg2);
  k_gemm1<<<(N0v + 127) / 128, 512, 0, stream>>>(x, Wt, H, as1, ad1, att_src1, att_dst1);

  k_count2x<<<(E1 + 255) / 256, 256, 0, stream>>>(dst1, E1, deg1, dst2, E2, deg2);
  k_scan2x<<<2, 1024, 0, stream>>>(deg1, rs1, cur1, N1v, deg2, rs2, cur2, N2v);
  k_scatter2x<<<(E1 + 255) / 256, 256, 0, stream>>>(src1, dst1, E1, cur1, es1,
                                                    src2, dst2, E2, cur2, es2);
  k_attn1<<<N1v / 4, 256, 0, stream>>>(as1, ad1, rs1, es1, H, b1, h1);
  k_l2feat<<<(N1v + 255) / 256, 256, 0, stream>>>(h1, W2, att_src2, att_dst2, g, as2, ad2);
  k_attn2<<<N2v / 4, 256, 0, stream>>>(as2, ad2, rs2, es2, g, b2, out);
}